// Round 7
// baseline (468.930 us; speedup 1.0000x reference)
//
#include <hip/hip_runtime.h>
#include <cstdint>
#include <cstddef>

typedef __bf16 bf16;
typedef __bf16 bf16x4 __attribute__((ext_vector_type(4)));
typedef __bf16 bf16x8 __attribute__((ext_vector_type(8)));
typedef float  f32x4  __attribute__((ext_vector_type(4)));
typedef unsigned int uint;

#define EPS 1e-5f

// ---------------------------------------------------------------------------
// async global->LDS, 16B per lane. LDS dest is wave-uniform base + lane*16.
// ---------------------------------------------------------------------------
__device__ __forceinline__ void load_lds16(const void* g, void* l) {
    typedef __attribute__((address_space(1))) void gvoid;
    typedef __attribute__((address_space(3))) void lvoid;
    gvoid* gp = (gvoid*)(unsigned long long)(uintptr_t)g;
    lvoid* lp = (lvoid*)(unsigned int)(uintptr_t)l;
    __builtin_amdgcn_global_load_lds(gp, lp, 16, 0, 0);
}

// ---------------------------------------------------------------------------
// FUSED prep: [0,1024) = convert_stats grid (64x16); [1024,4616) = weight
// prep (4 transposes + 4 scale/bias). One dispatch instead of two.
// ---------------------------------------------------------------------------
__global__ __launch_bounds__(256)
void prep_fused(const float* __restrict__ x, bf16* __restrict__ xb,
                float* __restrict__ p1, float* __restrict__ p2,
    const float* __restrict__ W1, const float* __restrict__ W2,
    const float* __restrict__ W3, const float* __restrict__ W4,
    bf16* __restrict__ t1, bf16* __restrict__ t2,
    bf16* __restrict__ t3, bf16* __restrict__ t4,
    const float* b1, const float* g1, const float* be1, const float* m1, const float* v1,
    const float* b2, const float* g2, const float* be2, const float* m2, const float* v2,
    const float* b3, const float* g3, const float* be3, const float* m3, const float* v3,
    const float* b4, const float* g4, const float* be4, const float* m4, const float* v4,
    float* __restrict__ sb)
{
    if (blockIdx.x < 1024) {
        // ---- convert_stats: float4 loads, bf16x4 stores, 4-rowgroup reduce
        __shared__ float sred[4][256], qred[4][256];
        const int b = blockIdx.x & 63, lc = blockIdx.x >> 6;
        const int cq = threadIdx.x & 63, rg = threadIdx.x >> 6;
        const int d0 = cq * 4;
        const size_t base = ((size_t)b * 1024 + lc * 64 + rg * 16) * 256;
        float s0 = 0, s1 = 0, s2 = 0, s3 = 0;
        float q0 = 0, q1 = 0, q2 = 0, q3 = 0;
        #pragma unroll 4
        for (int l = 0; l < 16; l++) {
            float4 v = *(const float4*)&x[base + (size_t)l * 256 + d0];
            bf16x4 bv;
            bv[0] = (bf16)v.x; bv[1] = (bf16)v.y; bv[2] = (bf16)v.z; bv[3] = (bf16)v.w;
            *(bf16x4*)&xb[base + (size_t)l * 256 + d0] = bv;
            s0 += v.x; s1 += v.y; s2 += v.z; s3 += v.w;
            q0 += v.x * v.x; q1 += v.y * v.y; q2 += v.z * v.z; q3 += v.w * v.w;
        }
        sred[rg][d0] = s0; sred[rg][d0 + 1] = s1; sred[rg][d0 + 2] = s2; sred[rg][d0 + 3] = s3;
        qred[rg][d0] = q0; qred[rg][d0 + 1] = q1; qred[rg][d0 + 2] = q2; qred[rg][d0 + 3] = q3;
        __syncthreads();
        if (rg == 0) {
            #pragma unroll
            for (int k = 0; k < 4; k++) {
                const int d = d0 + k;
                float ss = sred[0][d] + sred[1][d] + sred[2][d] + sred[3][d];
                float qq = qred[0][d] + qred[1][d] + qred[2][d] + qred[3][d];
                p1[((size_t)lc * 64 + b) * 256 + d] = ss;
                p2[((size_t)lc * 64 + b) * 256 + d] = qq;
            }
        }
        return;
    }
    // ---- weight prep (old prep_all, bid shifted by 1024)
    const int bid = blockIdx.x - 1024, tid = threadIdx.x;
    if (bid < 512) {                       // W1: 512x256 (Wt[n][k])
        int idx = bid * 256 + tid;
        int n = idx >> 8, k = idx & 255;
        t1[idx] = (bf16)W1[k * 512 + n];
    } else if (bid < 3584) {               // W2/W3/W4: 512x512 each
        int r = bid - 512;
        int which = r >> 10;               // 1024 blocks each
        int idx = (r & 1023) * 256 + tid;
        int n = idx >> 9, k = idx & 511;
        const float* W = which == 0 ? W2 : (which == 1 ? W3 : W4);
        bf16* Wt       = which == 0 ? t2 : (which == 1 ? t3 : t4);
        Wt[idx] = (bf16)W[k * 512 + n];
    } else {                               // scale/bias: 8 blocks
        int r = bid - 3584;
        int lay = r >> 1;
        int j = (r & 1) * 256 + tid;
        const float *b, *g, *be, *m, *v;
        switch (lay) {
            case 0: b=b1; g=g1; be=be1; m=m1; v=v1; break;
            case 1: b=b2; g=g2; be=be2; m=m2; v=v2; break;
            case 2: b=b3; g=g3; be=be3; m=m3; v=v3; break;
            default:b=b4; g=g4; be=be4; m=m4; v=v4; break;
        }
        float sj = g[j] * rsqrtf(v[j] + EPS);
        sb[lay * 1024 + j]       = sj;
        sb[lay * 1024 + 512 + j] = (b[j] - m[j]) * sj + be[j];
    }
}

// ---------------------------------------------------------------------------
// GEMM: C[M,512] = relu( (A[M,K] @ Wt[512,K]^T) * s + t ), bf16 out
// (round-5 structure, unchanged: 256x256 tile, BK=64, phased counted-vmcnt
// schedule, subtiled conflict-free LDS, LDS-staged coalesced epilogue)
// ---------------------------------------------------------------------------
template<int K>
__global__ __launch_bounds__(512, 2)
void gemm_bt(const bf16* __restrict__ A, const bf16* __restrict__ Bt,
             const float* __restrict__ sc, const float* __restrict__ bi,
             bf16* __restrict__ C)
{
    constexpr int NT = K / 64;                 // 4 (K=256) or 8 (K=512)
    __shared__ __align__(16) bf16 L[2][32768]; // 2 x 64KB

    const int tid  = threadIdx.x;
    const int lane = tid & 63;
    const int wid  = tid >> 6;                 // 0..7
    const int wm   = wid >> 2;                 // 0..1
    const int wn   = wid & 3;                  // 0..3
    const int quad = lane >> 4;
    const int l16  = lane & 15;

    // XCD-aware swizzle: 512 blocks, 8 XCDs, 64 consecutive per XCD.
    const int swz = (blockIdx.x & 7) * 64 + (blockIdx.x >> 3);
    const size_t m0 = (size_t)(swz >> 1) * 256;
    const int    n0 = (swz & 1) * 256;

    // staging: this wave covers fragment blocks b0,b1 of each chunk.
    const int b0 = wid * 2, b1 = b0 + 1;
    const bf16* pA0 = &A[(m0 + (size_t)((b0 >> 3) * 128 + ((b0 >> 1) & 3) * 16 + l16)) * K + (b0 & 1) * 32 + quad * 8];
    const bf16* pA1 = &A[(m0 + (size_t)((b1 >> 3) * 128 + ((b1 >> 1) & 3) * 16 + l16)) * K + (b1 & 1) * 32 + quad * 8];
    const bf16* pB0 = &Bt[(size_t)(n0 + (b0 >> 2) * 64 + ((b0 >> 1) & 1) * 16 + l16) * K + (b0 & 1) * 32 + quad * 8];
    const bf16* pB1 = &Bt[(size_t)(n0 + (b1 >> 2) * 64 + ((b1 >> 1) & 1) * 16 + l16) * K + (b1 & 1) * 32 + quad * 8];

    f32x4  acc[8][4] = {};
    bf16x8 aF[4][2], bF0[2][2], bF1[2][2];

    auto STAGE_A = [&](int kt, int ih, int buf) {
        load_lds16(pA0 + (size_t)ih * 64 * K + kt * 64, &L[buf][ih * 8192 + b0 * 512]);
        load_lds16(pA1 + (size_t)ih * 64 * K + kt * 64, &L[buf][ih * 8192 + b1 * 512]);
    };
    auto STAGE_B = [&](int kt, int jh, int buf) {
        load_lds16(pB0 + (size_t)jh * 32 * K + kt * 64, &L[buf][16384 + jh * 8192 + b0 * 512]);
        load_lds16(pB1 + (size_t)jh * 32 * K + kt * 64, &L[buf][16384 + jh * 8192 + b1 * 512]);
    };
    auto LOAD_A = [&](int cur, int ih) {
        #pragma unroll
        for (int il = 0; il < 4; il++)
            #pragma unroll
            for (int ks = 0; ks < 2; ks++)
                aF[il][ks] = *(const bf16x8*)&L[cur][ih * 8192 + (wm * 8 + il * 2 + ks) * 512 + lane * 8];
    };
    auto LOAD_B = [&](int cur, int jh, bf16x8 (&bf)[2][2]) {
        #pragma unroll
        for (int jl = 0; jl < 2; jl++)
            #pragma unroll
            for (int ks = 0; ks < 2; ks++)
                bf[jl][ks] = *(const bf16x8*)&L[cur][16384 + jh * 8192 + (wn * 4 + jl * 2 + ks) * 512 + lane * 8];
    };
    auto MFMA16 = [&](int ih, int jh, bf16x8 (&bf)[2][2]) {
        __builtin_amdgcn_s_setprio(1);
        #pragma unroll
        for (int ks = 0; ks < 2; ks++)
            #pragma unroll
            for (int il = 0; il < 4; il++)
                #pragma unroll
                for (int jl = 0; jl < 2; jl++)
                    acc[ih * 4 + il][jh * 2 + jl] = __builtin_amdgcn_mfma_f32_16x16x32_bf16(
                        aF[il][ks], bf[jl][ks], acc[ih * 4 + il][jh * 2 + jl], 0, 0, 0);
        __builtin_amdgcn_s_setprio(0);
    };

    // prologue: stage tile 0 (chunks A0,B0,B1,A1), validate A0,B0.
    STAGE_A(0, 0, 0); STAGE_B(0, 0, 0); STAGE_B(0, 1, 0); STAGE_A(0, 1, 0);
    asm volatile("s_waitcnt vmcnt(4)" ::: "memory");
    asm volatile("s_barrier" ::: "memory");

    for (int t = 0; t < NT; ++t) {
        const int cur = t & 1, nxt = cur ^ 1;
        const bool last = (t == NT - 1);
        // ---- phase 0: reads A0,B0 (validated prev ph3) ; MFMA(0,0)
        LOAD_A(cur, 0);
        LOAD_B(cur, 0, bF0);
        if (!last) {
            STAGE_A(t + 1, 0, nxt);
            asm volatile("s_waitcnt vmcnt(4)" ::: "memory");   // validates t:B1
        } else {
            asm volatile("s_waitcnt vmcnt(2)" ::: "memory");   // validates t:B1
        }
        asm volatile("s_barrier" ::: "memory");
        asm volatile("s_waitcnt lgkmcnt(0)" ::: "memory");
        MFMA16(0, 0, bF0);
        // ---- phase 1: reads B1 (validated ph0) ; MFMA(0,1)
        LOAD_B(cur, 1, bF1);
        if (!last) {
            STAGE_B(t + 1, 0, nxt);
            asm volatile("s_waitcnt vmcnt(4)" ::: "memory");   // validates t:A1
        } else {
            asm volatile("s_waitcnt vmcnt(0)" ::: "memory");   // validates t:A1
        }
        asm volatile("s_barrier" ::: "memory");
        asm volatile("s_waitcnt lgkmcnt(0)" ::: "memory");
        MFMA16(0, 1, bF1);
        // ---- phase 2: reads A1 (validated ph1) ; no barrier needed
        LOAD_A(cur, 1);
        if (!last) STAGE_B(t + 1, 1, nxt);
        asm volatile("s_waitcnt lgkmcnt(0)" ::: "memory");
        MFMA16(1, 0, bF0);
        // ---- phase 3: no reads ; validate t+1:A0,B0 for next ph0
        if (!last) {
            STAGE_A(t + 1, 1, nxt);
            asm volatile("s_waitcnt vmcnt(4)" ::: "memory");   // validates t+1:A0,B0
            asm volatile("s_barrier" ::: "memory");
        }
        MFMA16(1, 1, bF1);
    }

    // ---- epilogue: acc -> LDS (BN+relu fused) -> coalesced bf16x8 stores
    __syncthreads();                       // all waves done with K-loop LDS
    bf16* Lf = &L[0][0];                   // 65536 bf16 = full 256x256 C tile
    #pragma unroll
    for (int j = 0; j < 4; j++) {
        const int col = wn * 64 + j * 16 + l16;
        const float s = sc[n0 + col], t = bi[n0 + col];
        #pragma unroll
        for (int i = 0; i < 8; i++) {
            const int rowb = wm * 128 + i * 16 + quad * 4;
            #pragma unroll
            for (int r = 0; r < 4; r++) {
                float v = acc[i][j][r] * s + t;
                Lf[(rowb + r) * 256 + col] = (bf16)(v > 0.f ? v : 0.f);
            }
        }
    }
    __syncthreads();
    #pragma unroll
    for (int c = 0; c < 16; c++) {
        const int e = c * 4096 + tid * 8;
        const int row = e >> 8, col = e & 255;
        *(bf16x8*)&C[(m0 + row) * 512 + n0 + col] = *(const bf16x8*)&Lf[e];
    }
}

// ---------------------------------------------------------------------------
// A[N,8] = h4[N,512](bf16) @ Wa[512,8](f32)
// ---------------------------------------------------------------------------
__global__ __launch_bounds__(256)
void compute_A(const bf16* __restrict__ h, const float* __restrict__ Wa,
               float* __restrict__ A)
{
    __shared__ float WaL[512 * 8];
    const int tid = threadIdx.x;
    for (int i = tid; i < 4096; i += 256) WaL[i] = Wa[i];
    __syncthreads();
    const size_t row = (size_t)blockIdx.x * 32 + (tid >> 3);
    const int r = tid & 7;
    const bf16* hp = h + row * 512;
    float acc0 = 0.f, acc1 = 0.f;
    #pragma unroll 4
    for (int k8 = 0; k8 < 64; k8 += 2) {
        bf16x8 h0 = *(const bf16x8*)&hp[k8 * 8];
        bf16x8 h1 = *(const bf16x8*)&hp[k8 * 8 + 8];
        #pragma unroll
        for (int j = 0; j < 8; j++) {
            acc0 += (float)h0[j] * WaL[(k8 * 8 + j) * 8 + r];
            acc1 += (float)h1[j] * WaL[(k8 * 8 + 8 + j) * 8 + r];
        }
    }
    A[row * 8 + r] = acc0 + acc1;
}

// ---------------------------------------------------------------------------
// per-segment softmax over L (8 cols) + penalty. 1024 threads.
// v2: AsL padded to stride 9 (was 8): bank = (8c+r+9l')&31 -> 2 lanes/bank
// = conflict-free (was 8-way on EVERY read). penb[b] per-block write
// (no atomic, no memset needed).
// ---------------------------------------------------------------------------
__global__ __launch_bounds__(1024)
void seg_softmax(const float* __restrict__ A, float* __restrict__ Asg,
                 float* __restrict__ penb)
{
    __shared__ float AsL[1024 * 9];
    __shared__ float red[1024];
    __shared__ float amax[8], asum[8];
    const int b = blockIdx.x, tid = threadIdx.x;
    const float* Ab = A + (size_t)b * 8192;
    for (int i = tid * 4; i < 8192; i += 4096) {
        float4 v = *(const float4*)&Ab[i];
        const int l = i >> 3, r0 = i & 7;          // r0 in {0,4}
        AsL[l * 9 + r0]     = v.x;
        AsL[l * 9 + r0 + 1] = v.y;
        AsL[l * 9 + r0 + 2] = v.z;
        AsL[l * 9 + r0 + 3] = v.w;
    }
    __syncthreads();
    const int r = tid & 7, chunk = tid >> 3;      // 128 chunks x 8 rows
    float pm = -1e30f;
    for (int l = chunk * 8; l < chunk * 8 + 8; l++) pm = fmaxf(pm, AsL[l * 9 + r]);
    red[tid] = pm;
    __syncthreads();
    if (tid < 512) red[tid] = fmaxf(red[tid], red[tid + 512]); __syncthreads();
    if (tid < 256) red[tid] = fmaxf(red[tid], red[tid + 256]); __syncthreads();
    if (tid < 128) red[tid] = fmaxf(red[tid], red[tid + 128]); __syncthreads();
    if (tid <  64) red[tid] = fmaxf(red[tid], red[tid +  64]); __syncthreads();
    if (tid <  32) red[tid] = fmaxf(red[tid], red[tid +  32]); __syncthreads();
    if (tid <  16) red[tid] = fmaxf(red[tid], red[tid +  16]); __syncthreads();
    if (tid <   8) amax[tid] = fmaxf(red[tid], red[tid + 8]);  __syncthreads();
    const float mr = amax[r];
    float ps = 0.f;
    for (int l = chunk * 8; l < chunk * 8 + 8; l++) {
        float e = expf(AsL[l * 9 + r] - mr);
        AsL[l * 9 + r] = e;
        ps += e;
    }
    red[tid] = ps;
    __syncthreads();
    if (tid < 512) red[tid] += red[tid + 512]; __syncthreads();
    if (tid < 256) red[tid] += red[tid + 256]; __syncthreads();
    if (tid < 128) red[tid] += red[tid + 128]; __syncthreads();
    if (tid <  64) red[tid] += red[tid +  64]; __syncthreads();
    if (tid <  32) red[tid] += red[tid +  32]; __syncthreads();
    if (tid <  16) red[tid] += red[tid +  16]; __syncthreads();
    if (tid <   8) asum[tid] = red[tid] + red[tid + 8];        __syncthreads();
    const float inv = 1.f / asum[r];
    for (int l = chunk * 8; l < chunk * 8 + 8; l++) AsL[l * 9 + r] *= inv;
    __syncthreads();
    for (int i = tid * 4; i < 8192; i += 4096) {
        const int l = i >> 3, r0 = i & 7;
        float4 v;
        v.x = AsL[l * 9 + r0];
        v.y = AsL[l * 9 + r0 + 1];
        v.z = AsL[l * 9 + r0 + 2];
        v.w = AsL[l * 9 + r0 + 3];
        *(float4*)&Asg[(size_t)b * 8192 + i] = v;
    }
    __syncthreads();
    // penalty: 64 (rr,ss) pairs x 16 l-chunks of 64
    {
        const int p = tid & 63, ch = tid >> 6;
        const int rr = p >> 3, ss = p & 7;
        float dot = 0.f;
        for (int l = ch * 64; l < ch * 64 + 64; l++)
            dot += AsL[l * 9 + rr] * AsL[l * 9 + ss];
        red[tid] = dot;
    }
    __syncthreads();
    if (tid < 512) red[tid] += red[tid + 512]; __syncthreads();
    if (tid < 256) red[tid] += red[tid + 256]; __syncthreads();
    if (tid < 128) red[tid] += red[tid + 128]; __syncthreads();
    if (tid < 64) {
        float d = red[tid] + red[tid + 64] - 1.f;
        red[tid] = d * d;
    }
    __syncthreads();
    if (tid == 0) {
        float s = 0.f;
        for (int i = 0; i < 64; i++) s += red[i];
        penb[b] = s;
    }
}

// ---------------------------------------------------------------------------
// pooled partials: grid (64 b, 8 lc of 128 rows), 256 thr. (unchanged)
// ---------------------------------------------------------------------------
__global__ __launch_bounds__(256)
void pooled_k(const float* __restrict__ Asg, const bf16* __restrict__ h,
              float* __restrict__ pp)
{
    __shared__ float AsL[128 * 8];    // 4 KB: As rows for this lc
    __shared__ float red[256 * 8];    // 8 KB: cross-rowgroup reduce
    const int b = blockIdx.x, lc = blockIdx.y;
    const int tid = threadIdx.x;
    const int cg = tid & 63;          // col group: cols cg*8..+7 (512 cols)
    const int lg = tid >> 6;          // row group: 32 rows each

    *(float4*)&AsL[tid * 4] = *(const float4*)&Asg[(size_t)b * 8192 + lc * 1024 + tid * 4];
    __syncthreads();

    float acc[8][8] = {};
    const bf16* hb = h + ((size_t)b * 1024 + lc * 128 + lg * 32) * 512 + cg * 8;
    #pragma unroll 2
    for (int l = 0; l < 32; l++) {
        bf16x8 hv = *(const bf16x8*)&hb[(size_t)l * 512];
        float hf[8];
        #pragma unroll
        for (int k = 0; k < 8; k++) hf[k] = (float)hv[k];
        const float* ar = &AsL[(lg * 32 + l) * 8];
        #pragma unroll
        for (int r = 0; r < 8; r++)
            #pragma unroll
            for (int k = 0; k < 8; k++)
                acc[r][k] += ar[r] * hf[k];
    }

    float* pb = pp + ((size_t)lc * 64 + b) * 4096;
    #pragma unroll
    for (int r = 0; r < 8; r++) {
        __syncthreads();
        *(float4*)&red[tid * 8]     = *(float4*)&acc[r][0];
        *(float4*)&red[tid * 8 + 4] = *(float4*)&acc[r][4];
        __syncthreads();
        if (tid < 64) {
            #pragma unroll
            for (int k = 0; k < 8; k++) {
                float v = red[tid * 8 + k] + red[(tid + 64) * 8 + k]
                        + red[(tid + 128) * 8 + k] + red[(tid + 192) * 8 + k];
                pb[r * 512 + tid * 8 + k] = v;
            }
        }
    }
}

// ---------------------------------------------------------------------------
// FUSED head: build f[4608] (pooled sum + mean/std), z = f @ Wo1 (4-way
// j-split + LDS reduce), BN+relu, @Wo2, log_softmax, penalty sum.
// 64 blocks x 512 thr. Replaces head1 (64x9 + atomics) + head2 + memset.
// ---------------------------------------------------------------------------
__global__ __launch_bounds__(512)
void head(const float* __restrict__ pp, const float* __restrict__ p1,
          const float* __restrict__ p2, const float* __restrict__ Wo1,
          const float* __restrict__ bo1, const float* __restrict__ go,
          const float* __restrict__ beo, const float* __restrict__ mo,
          const float* __restrict__ vo, const float* __restrict__ Wo2,
          const float* __restrict__ bo2, const float* __restrict__ penb,
          float* __restrict__ out)
{
    __shared__ float f[4608];
    __shared__ float zred[512];
    __shared__ float o[128];
    __shared__ float lg[4];
    const int b = blockIdx.x, tid = threadIdx.x;
    for (int j = tid; j < 4096; j += 512) {
        float s = 0.f;
        #pragma unroll
        for (int lc = 0; lc < 8; lc++)
            s += pp[((size_t)lc * 64 + b) * 4096 + j];
        f[j] = s;
    }
    if (tid < 256) {
        float s = 0.f, s2 = 0.f;
        #pragma unroll
        for (int lc = 0; lc < 16; lc++) {
            s  += p1[((size_t)lc * 64 + b) * 256 + tid];
            s2 += p2[((size_t)lc * 64 + b) * 256 + tid];
        }
        float m = s * (1.f / 1024.f);
        float var = (s2 - s * m) * (1.f / 1023.f);
        f[4096 + tid] = m;
        f[4352 + tid] = sqrtf(fmaxf(var, 0.f));
    }
    __syncthreads();
    const int col = tid & 127, part = tid >> 7;    // 4 parts x 1152 j's
    float z = 0.f;
    const float* Wp = Wo1 + (size_t)part * 1152 * 128 + col;
    const float* fp = f + part * 1152;
    #pragma unroll 8
    for (int j = 0; j < 1152; j++) z += fp[j] * Wp[(size_t)j * 128];
    zred[tid] = z;
    __syncthreads();
    if (tid < 128) {
        float zz = zred[tid] + zred[tid + 128] + zred[tid + 256] + zred[tid + 384];
        float s = go[tid] * rsqrtf(vo[tid] + EPS);
        float t = (bo1[tid] - mo[tid]) * s + beo[tid];
        float ov = zz * s + t;
        o[tid] = ov > 0.f ? ov : 0.f;
    }
    __syncthreads();
    if (tid < 4) {
        float acc = bo2[tid];
        for (int j = 0; j < 128; j++) acc += o[j] * Wo2[j * 4 + tid];
        lg[tid] = acc;
    }
    __syncthreads();
    if (tid == 0) {
        float m = fmaxf(fmaxf(lg[0], lg[1]), fmaxf(lg[2], lg[3]));
        float sum = 0.f;
        for (int k = 0; k < 4; k++) sum += expf(lg[k] - m);
        float lse = m + logf(sum);
        for (int k = 0; k < 4; k++) out[b * 4 + k] = lg[k] - lse;
        if (b == 0) {
            float psum = 0.f;
            for (int i = 0; i < 64; i++) psum += penb[i];
            out[256] = psum;
        }
    }
}

// ---------------------------------------------------------------------------
extern "C" void kernel_launch(void* const* d_in, const int* in_sizes, int n_in,
                              void* d_out, int out_size, void* d_ws, size_t ws_size,
                              hipStream_t stream)
{
    const float* x   = (const float*)d_in[0];
    const float* Wa  = (const float*)d_in[2];
    const float* Wo1 = (const float*)d_in[3];
    const float* bo1 = (const float*)d_in[4];
    const float* go  = (const float*)d_in[5];
    const float* beo = (const float*)d_in[6];
    const float* mo  = (const float*)d_in[7];
    const float* vo  = (const float*)d_in[8];
    const float* Wo2 = (const float*)d_in[9];
    const float* bo2 = (const float*)d_in[10];
    const float *W[4], *bb[4], *gg[4], *be[4], *mm[4], *vv[4];
    for (int l = 0; l < 4; l++) {
        W[l]  = (const float*)d_in[11 + 6 * l + 0];
        bb[l] = (const float*)d_in[11 + 6 * l + 1];
        gg[l] = (const float*)d_in[11 + 6 * l + 2];
        be[l] = (const float*)d_in[11 + 6 * l + 3];
        mm[l] = (const float*)d_in[11 + 6 * l + 4];
        vv[l] = (const float*)d_in[11 + 6 * l + 5];
    }

    char* w = (char*)d_ws;
    bf16* xb  = (bf16*)w;  w += (size_t)65536 * 256 * 2;   // 32 MB
    bf16* hA  = (bf16*)w;  w += (size_t)65536 * 512 * 2;   // 64 MB
    bf16* hB  = (bf16*)w;  w += (size_t)65536 * 512 * 2;   // 64 MB
    bf16* w1t = (bf16*)w;  w += (size_t)512 * 256 * 2;
    bf16* w2t = (bf16*)w;  w += (size_t)512 * 512 * 2;
    bf16* w3t = (bf16*)w;  w += (size_t)512 * 512 * 2;
    bf16* w4t = (bf16*)w;  w += (size_t)512 * 512 * 2;
    float* sb = (float*)w; w += (size_t)4 * 1024 * 4;      // [layer][s|t][512]
    float* Ab = (float*)w; w += (size_t)65536 * 8 * 4;
    float* As = (float*)w; w += (size_t)65536 * 8 * 4;
    float* pp = (float*)w; w += (size_t)8 * 64 * 4096 * 4; // pooled partials
    float* p1 = (float*)w; w += (size_t)16 * 64 * 256 * 4;
    float* p2 = (float*)w; w += (size_t)16 * 64 * 256 * 4;
    float* penb = (float*)w; w += (size_t)64 * 4;

    prep_fused<<<4616, 256, 0, stream>>>(
        x, xb, p1, p2,
        W[0], W[1], W[2], W[3], w1t, w2t, w3t, w4t,
        bb[0], gg[0], be[0], mm[0], vv[0],
        bb[1], gg[1], be[1], mm[1], vv[1],
        bb[2], gg[2], be[2], mm[2], vv[2],
        bb[3], gg[3], be[3], mm[3], vv[3], sb);

    gemm_bt<256><<<512, 512, 0, stream>>>(xb, w1t, sb + 0,    sb + 512,  hA);
    gemm_bt<512><<<512, 512, 0, stream>>>(hA, w2t, sb + 1024, sb + 1536, hB);
    gemm_bt<512><<<512, 512, 0, stream>>>(hB, w3t, sb + 2048, sb + 2560, hA);
    gemm_bt<512><<<512, 512, 0, stream>>>(hA, w4t, sb + 3072, sb + 3584, hB);

    compute_A<<<2048, 256, 0, stream>>>(hB, Wa, Ab);
    seg_softmax<<<64, 1024, 0, stream>>>(Ab, As, penb);
    pooled_k<<<dim3(64, 8), 256, 0, stream>>>(As, hB, pp);
    head<<<64, 512, 0, stream>>>(pp, p1, p2, Wo1, bo1, go, beo, mo, vo,
                                 Wo2, bo2, penb, (float*)d_out);
}

// Round 8
// 429.323 us; speedup vs baseline: 1.0923x; 1.0923x over previous
//
#include <hip/hip_runtime.h>
#include <cstdint>
#include <cstddef>

typedef __bf16 bf16;
typedef __bf16 bf16x4 __attribute__((ext_vector_type(4)));
typedef __bf16 bf16x8 __attribute__((ext_vector_type(8)));
typedef float  f32x4  __attribute__((ext_vector_type(4)));
typedef unsigned int uint;

#define EPS 1e-5f

// ---------------------------------------------------------------------------
// async global->LDS, 16B per lane. LDS dest is wave-uniform base + lane*16.
// ---------------------------------------------------------------------------
__device__ __forceinline__ void load_lds16(const void* g, void* l) {
    typedef __attribute__((address_space(1))) void gvoid;
    typedef __attribute__((address_space(3))) void lvoid;
    gvoid* gp = (gvoid*)(unsigned long long)(uintptr_t)g;
    lvoid* lp = (lvoid*)(unsigned int)(uintptr_t)l;
    __builtin_amdgcn_global_load_lds(gp, lp, 16, 0, 0);
}

// ---------------------------------------------------------------------------
// FUSED prep: [0,1024) = convert_stats grid (64x16); [1024,4616) = weight
// prep (4 transposes + 4 scale/bias). One dispatch instead of two.
// ---------------------------------------------------------------------------
__global__ __launch_bounds__(256)
void prep_fused(const float* __restrict__ x, bf16* __restrict__ xb,
                float* __restrict__ p1, float* __restrict__ p2,
    const float* __restrict__ W1, const float* __restrict__ W2,
    const float* __restrict__ W3, const float* __restrict__ W4,
    bf16* __restrict__ t1, bf16* __restrict__ t2,
    bf16* __restrict__ t3, bf16* __restrict__ t4,
    const float* b1, const float* g1, const float* be1, const float* m1, const float* v1,
    const float* b2, const float* g2, const float* be2, const float* m2, const float* v2,
    const float* b3, const float* g3, const float* be3, const float* m3, const float* v3,
    const float* b4, const float* g4, const float* be4, const float* m4, const float* v4,
    float* __restrict__ sb)
{
    if (blockIdx.x < 1024) {
        // ---- convert_stats: float4 loads, bf16x4 stores, 4-rowgroup reduce
        __shared__ float sred[4][256], qred[4][256];
        const int b = blockIdx.x & 63, lc = blockIdx.x >> 6;
        const int cq = threadIdx.x & 63, rg = threadIdx.x >> 6;
        const int d0 = cq * 4;
        const size_t base = ((size_t)b * 1024 + lc * 64 + rg * 16) * 256;
        float s0 = 0, s1 = 0, s2 = 0, s3 = 0;
        float q0 = 0, q1 = 0, q2 = 0, q3 = 0;
        #pragma unroll 4
        for (int l = 0; l < 16; l++) {
            float4 v = *(const float4*)&x[base + (size_t)l * 256 + d0];
            bf16x4 bv;
            bv[0] = (bf16)v.x; bv[1] = (bf16)v.y; bv[2] = (bf16)v.z; bv[3] = (bf16)v.w;
            *(bf16x4*)&xb[base + (size_t)l * 256 + d0] = bv;
            s0 += v.x; s1 += v.y; s2 += v.z; s3 += v.w;
            q0 += v.x * v.x; q1 += v.y * v.y; q2 += v.z * v.z; q3 += v.w * v.w;
        }
        sred[rg][d0] = s0; sred[rg][d0 + 1] = s1; sred[rg][d0 + 2] = s2; sred[rg][d0 + 3] = s3;
        qred[rg][d0] = q0; qred[rg][d0 + 1] = q1; qred[rg][d0 + 2] = q2; qred[rg][d0 + 3] = q3;
        __syncthreads();
        if (rg == 0) {
            #pragma unroll
            for (int k = 0; k < 4; k++) {
                const int d = d0 + k;
                float ss = sred[0][d] + sred[1][d] + sred[2][d] + sred[3][d];
                float qq = qred[0][d] + qred[1][d] + qred[2][d] + qred[3][d];
                p1[((size_t)lc * 64 + b) * 256 + d] = ss;
                p2[((size_t)lc * 64 + b) * 256 + d] = qq;
            }
        }
        return;
    }
    // ---- weight prep (old prep_all, bid shifted by 1024)
    const int bid = blockIdx.x - 1024, tid = threadIdx.x;
    if (bid < 512) {                       // W1: 512x256 (Wt[n][k])
        int idx = bid * 256 + tid;
        int n = idx >> 8, k = idx & 255;
        t1[idx] = (bf16)W1[k * 512 + n];
    } else if (bid < 3584) {               // W2/W3/W4: 512x512 each
        int r = bid - 512;
        int which = r >> 10;               // 1024 blocks each
        int idx = (r & 1023) * 256 + tid;
        int n = idx >> 9, k = idx & 511;
        const float* W = which == 0 ? W2 : (which == 1 ? W3 : W4);
        bf16* Wt       = which == 0 ? t2 : (which == 1 ? t3 : t4);
        Wt[idx] = (bf16)W[k * 512 + n];
    } else {                               // scale/bias: 8 blocks
        int r = bid - 3584;
        int lay = r >> 1;
        int j = (r & 1) * 256 + tid;
        const float *b, *g, *be, *m, *v;
        switch (lay) {
            case 0: b=b1; g=g1; be=be1; m=m1; v=v1; break;
            case 1: b=b2; g=g2; be=be2; m=m2; v=v2; break;
            case 2: b=b3; g=g3; be=be3; m=m3; v=v3; break;
            default:b=b4; g=g4; be=be4; m=m4; v=v4; break;
        }
        float sj = g[j] * rsqrtf(v[j] + EPS);
        sb[lay * 1024 + j]       = sj;
        sb[lay * 1024 + 512 + j] = (b[j] - m[j]) * sj + be[j];
    }
}

// ---------------------------------------------------------------------------
// GEMM: C[M,512] = relu( (A[M,K] @ Wt[512,K]^T) * s + t ), bf16 out
// (round-5 structure, unchanged: 256x256 tile, BK=64, phased counted-vmcnt
// schedule, subtiled conflict-free LDS, LDS-staged coalesced epilogue)
// ---------------------------------------------------------------------------
template<int K>
__global__ __launch_bounds__(512, 2)
void gemm_bt(const bf16* __restrict__ A, const bf16* __restrict__ Bt,
             const float* __restrict__ sc, const float* __restrict__ bi,
             bf16* __restrict__ C)
{
    constexpr int NT = K / 64;                 // 4 (K=256) or 8 (K=512)
    __shared__ __align__(16) bf16 L[2][32768]; // 2 x 64KB

    const int tid  = threadIdx.x;
    const int lane = tid & 63;
    const int wid  = tid >> 6;                 // 0..7
    const int wm   = wid >> 2;                 // 0..1
    const int wn   = wid & 3;                  // 0..3
    const int quad = lane >> 4;
    const int l16  = lane & 15;

    // XCD-aware swizzle: 512 blocks, 8 XCDs, 64 consecutive per XCD.
    const int swz = (blockIdx.x & 7) * 64 + (blockIdx.x >> 3);
    const size_t m0 = (size_t)(swz >> 1) * 256;
    const int    n0 = (swz & 1) * 256;

    // staging: this wave covers fragment blocks b0,b1 of each chunk.
    const int b0 = wid * 2, b1 = b0 + 1;
    const bf16* pA0 = &A[(m0 + (size_t)((b0 >> 3) * 128 + ((b0 >> 1) & 3) * 16 + l16)) * K + (b0 & 1) * 32 + quad * 8];
    const bf16* pA1 = &A[(m0 + (size_t)((b1 >> 3) * 128 + ((b1 >> 1) & 3) * 16 + l16)) * K + (b1 & 1) * 32 + quad * 8];
    const bf16* pB0 = &Bt[(size_t)(n0 + (b0 >> 2) * 64 + ((b0 >> 1) & 1) * 16 + l16) * K + (b0 & 1) * 32 + quad * 8];
    const bf16* pB1 = &Bt[(size_t)(n0 + (b1 >> 2) * 64 + ((b1 >> 1) & 1) * 16 + l16) * K + (b1 & 1) * 32 + quad * 8];

    f32x4  acc[8][4] = {};
    bf16x8 aF[4][2], bF0[2][2], bF1[2][2];

    auto STAGE_A = [&](int kt, int ih, int buf) {
        load_lds16(pA0 + (size_t)ih * 64 * K + kt * 64, &L[buf][ih * 8192 + b0 * 512]);
        load_lds16(pA1 + (size_t)ih * 64 * K + kt * 64, &L[buf][ih * 8192 + b1 * 512]);
    };
    auto STAGE_B = [&](int kt, int jh, int buf) {
        load_lds16(pB0 + (size_t)jh * 32 * K + kt * 64, &L[buf][16384 + jh * 8192 + b0 * 512]);
        load_lds16(pB1 + (size_t)jh * 32 * K + kt * 64, &L[buf][16384 + jh * 8192 + b1 * 512]);
    };
    auto LOAD_A = [&](int cur, int ih) {
        #pragma unroll
        for (int il = 0; il < 4; il++)
            #pragma unroll
            for (int ks = 0; ks < 2; ks++)
                aF[il][ks] = *(const bf16x8*)&L[cur][ih * 8192 + (wm * 8 + il * 2 + ks) * 512 + lane * 8];
    };
    auto LOAD_B = [&](int cur, int jh, bf16x8 (&bf)[2][2]) {
        #pragma unroll
        for (int jl = 0; jl < 2; jl++)
            #pragma unroll
            for (int ks = 0; ks < 2; ks++)
                bf[jl][ks] = *(const bf16x8*)&L[cur][16384 + jh * 8192 + (wn * 4 + jl * 2 + ks) * 512 + lane * 8];
    };
    auto MFMA16 = [&](int ih, int jh, bf16x8 (&bf)[2][2]) {
        __builtin_amdgcn_s_setprio(1);
        #pragma unroll
        for (int ks = 0; ks < 2; ks++)
            #pragma unroll
            for (int il = 0; il < 4; il++)
                #pragma unroll
                for (int jl = 0; jl < 2; jl++)
                    acc[ih * 4 + il][jh * 2 + jl] = __builtin_amdgcn_mfma_f32_16x16x32_bf16(
                        aF[il][ks], bf[jl][ks], acc[ih * 4 + il][jh * 2 + jl], 0, 0, 0);
        __builtin_amdgcn_s_setprio(0);
    };

    // prologue: stage tile 0 (chunks A0,B0,B1,A1), validate A0,B0.
    STAGE_A(0, 0, 0); STAGE_B(0, 0, 0); STAGE_B(0, 1, 0); STAGE_A(0, 1, 0);
    asm volatile("s_waitcnt vmcnt(4)" ::: "memory");
    asm volatile("s_barrier" ::: "memory");

    for (int t = 0; t < NT; ++t) {
        const int cur = t & 1, nxt = cur ^ 1;
        const bool last = (t == NT - 1);
        // ---- phase 0: reads A0,B0 (validated prev ph3) ; MFMA(0,0)
        LOAD_A(cur, 0);
        LOAD_B(cur, 0, bF0);
        if (!last) {
            STAGE_A(t + 1, 0, nxt);
            asm volatile("s_waitcnt vmcnt(4)" ::: "memory");   // validates t:B1
        } else {
            asm volatile("s_waitcnt vmcnt(2)" ::: "memory");   // validates t:B1
        }
        asm volatile("s_barrier" ::: "memory");
        asm volatile("s_waitcnt lgkmcnt(0)" ::: "memory");
        MFMA16(0, 0, bF0);
        // ---- phase 1: reads B1 (validated ph0) ; MFMA(0,1)
        LOAD_B(cur, 1, bF1);
        if (!last) {
            STAGE_B(t + 1, 0, nxt);
            asm volatile("s_waitcnt vmcnt(4)" ::: "memory");   // validates t:A1
        } else {
            asm volatile("s_waitcnt vmcnt(0)" ::: "memory");   // validates t:A1
        }
        asm volatile("s_barrier" ::: "memory");
        asm volatile("s_waitcnt lgkmcnt(0)" ::: "memory");
        MFMA16(0, 1, bF1);
        // ---- phase 2: reads A1 (validated ph1) ; no barrier needed
        LOAD_A(cur, 1);
        if (!last) STAGE_B(t + 1, 1, nxt);
        asm volatile("s_waitcnt lgkmcnt(0)" ::: "memory");
        MFMA16(1, 0, bF0);
        // ---- phase 3: no reads ; validate t+1:A0,B0 for next ph0
        if (!last) {
            STAGE_A(t + 1, 1, nxt);
            asm volatile("s_waitcnt vmcnt(4)" ::: "memory");   // validates t+1:A0,B0
            asm volatile("s_barrier" ::: "memory");
        }
        MFMA16(1, 1, bF1);
    }

    // ---- epilogue: acc -> LDS (BN+relu fused) -> coalesced bf16x8 stores
    __syncthreads();                       // all waves done with K-loop LDS
    bf16* Lf = &L[0][0];                   // 65536 bf16 = full 256x256 C tile
    #pragma unroll
    for (int j = 0; j < 4; j++) {
        const int col = wn * 64 + j * 16 + l16;
        const float s = sc[n0 + col], t = bi[n0 + col];
        #pragma unroll
        for (int i = 0; i < 8; i++) {
            const int rowb = wm * 128 + i * 16 + quad * 4;
            #pragma unroll
            for (int r = 0; r < 4; r++) {
                float v = acc[i][j][r] * s + t;
                Lf[(rowb + r) * 256 + col] = (bf16)(v > 0.f ? v : 0.f);
            }
        }
    }
    __syncthreads();
    #pragma unroll
    for (int c = 0; c < 16; c++) {
        const int e = c * 4096 + tid * 8;
        const int row = e >> 8, col = e & 255;
        *(bf16x8*)&C[(m0 + row) * 512 + n0 + col] = *(const bf16x8*)&Lf[e];
    }
}

// ---------------------------------------------------------------------------
// A[N,8] = h4[N,512](bf16) @ Wa[512,8](f32)
// ---------------------------------------------------------------------------
__global__ __launch_bounds__(256)
void compute_A(const bf16* __restrict__ h, const float* __restrict__ Wa,
               float* __restrict__ A)
{
    __shared__ float WaL[512 * 8];
    const int tid = threadIdx.x;
    for (int i = tid; i < 4096; i += 256) WaL[i] = Wa[i];
    __syncthreads();
    const size_t row = (size_t)blockIdx.x * 32 + (tid >> 3);
    const int r = tid & 7;
    const bf16* hp = h + row * 512;
    float acc0 = 0.f, acc1 = 0.f;
    #pragma unroll 4
    for (int k8 = 0; k8 < 64; k8 += 2) {
        bf16x8 h0 = *(const bf16x8*)&hp[k8 * 8];
        bf16x8 h1 = *(const bf16x8*)&hp[k8 * 8 + 8];
        #pragma unroll
        for (int j = 0; j < 8; j++) {
            acc0 += (float)h0[j] * WaL[(k8 * 8 + j) * 8 + r];
            acc1 += (float)h1[j] * WaL[(k8 * 8 + 8 + j) * 8 + r];
        }
    }
    A[row * 8 + r] = acc0 + acc1;
}

// ---------------------------------------------------------------------------
// per-segment softmax over L (8 cols) + penalty. 1024 threads.
// AsL padded to stride 9: bank = (8c+r+9l')&31 -> 2 lanes/bank = free.
// penb[b] per-block write (no atomic, no memset).
// ---------------------------------------------------------------------------
__global__ __launch_bounds__(1024)
void seg_softmax(const float* __restrict__ A, float* __restrict__ Asg,
                 float* __restrict__ penb)
{
    __shared__ float AsL[1024 * 9];
    __shared__ float red[1024];
    __shared__ float amax[8], asum[8];
    const int b = blockIdx.x, tid = threadIdx.x;
    const float* Ab = A + (size_t)b * 8192;
    for (int i = tid * 4; i < 8192; i += 4096) {
        float4 v = *(const float4*)&Ab[i];
        const int l = i >> 3, r0 = i & 7;          // r0 in {0,4}
        AsL[l * 9 + r0]     = v.x;
        AsL[l * 9 + r0 + 1] = v.y;
        AsL[l * 9 + r0 + 2] = v.z;
        AsL[l * 9 + r0 + 3] = v.w;
    }
    __syncthreads();
    const int r = tid & 7, chunk = tid >> 3;      // 128 chunks x 8 rows
    float pm = -1e30f;
    for (int l = chunk * 8; l < chunk * 8 + 8; l++) pm = fmaxf(pm, AsL[l * 9 + r]);
    red[tid] = pm;
    __syncthreads();
    if (tid < 512) red[tid] = fmaxf(red[tid], red[tid + 512]); __syncthreads();
    if (tid < 256) red[tid] = fmaxf(red[tid], red[tid + 256]); __syncthreads();
    if (tid < 128) red[tid] = fmaxf(red[tid], red[tid + 128]); __syncthreads();
    if (tid <  64) red[tid] = fmaxf(red[tid], red[tid +  64]); __syncthreads();
    if (tid <  32) red[tid] = fmaxf(red[tid], red[tid +  32]); __syncthreads();
    if (tid <  16) red[tid] = fmaxf(red[tid], red[tid +  16]); __syncthreads();
    if (tid <   8) amax[tid] = fmaxf(red[tid], red[tid + 8]);  __syncthreads();
    const float mr = amax[r];
    float ps = 0.f;
    for (int l = chunk * 8; l < chunk * 8 + 8; l++) {
        float e = expf(AsL[l * 9 + r] - mr);
        AsL[l * 9 + r] = e;
        ps += e;
    }
    red[tid] = ps;
    __syncthreads();
    if (tid < 512) red[tid] += red[tid + 512]; __syncthreads();
    if (tid < 256) red[tid] += red[tid + 256]; __syncthreads();
    if (tid < 128) red[tid] += red[tid + 128]; __syncthreads();
    if (tid <  64) red[tid] += red[tid +  64]; __syncthreads();
    if (tid <  32) red[tid] += red[tid +  32]; __syncthreads();
    if (tid <  16) red[tid] += red[tid +  16]; __syncthreads();
    if (tid <   8) asum[tid] = red[tid] + red[tid + 8];        __syncthreads();
    const float inv = 1.f / asum[r];
    for (int l = chunk * 8; l < chunk * 8 + 8; l++) AsL[l * 9 + r] *= inv;
    __syncthreads();
    for (int i = tid * 4; i < 8192; i += 4096) {
        const int l = i >> 3, r0 = i & 7;
        float4 v;
        v.x = AsL[l * 9 + r0];
        v.y = AsL[l * 9 + r0 + 1];
        v.z = AsL[l * 9 + r0 + 2];
        v.w = AsL[l * 9 + r0 + 3];
        *(float4*)&Asg[(size_t)b * 8192 + i] = v;
    }
    __syncthreads();
    // penalty: 64 (rr,ss) pairs x 16 l-chunks of 64
    {
        const int p = tid & 63, ch = tid >> 6;
        const int rr = p >> 3, ss = p & 7;
        float dot = 0.f;
        for (int l = ch * 64; l < ch * 64 + 64; l++)
            dot += AsL[l * 9 + rr] * AsL[l * 9 + ss];
        red[tid] = dot;
    }
    __syncthreads();
    if (tid < 512) red[tid] += red[tid + 512]; __syncthreads();
    if (tid < 256) red[tid] += red[tid + 256]; __syncthreads();
    if (tid < 128) red[tid] += red[tid + 128]; __syncthreads();
    if (tid < 64) {
        float d = red[tid] + red[tid + 64] - 1.f;
        red[tid] = d * d;
    }
    __syncthreads();
    if (tid == 0) {
        float s = 0.f;
        for (int i = 0; i < 64; i++) s += red[i];
        penb[b] = s;
    }
}

// ---------------------------------------------------------------------------
// pooled partials: grid (64 b, 8 lc of 128 rows), 256 thr. (unchanged)
// ---------------------------------------------------------------------------
__global__ __launch_bounds__(256)
void pooled_k(const float* __restrict__ Asg, const bf16* __restrict__ h,
              float* __restrict__ pp)
{
    __shared__ float AsL[128 * 8];    // 4 KB: As rows for this lc
    __shared__ float red[256 * 8];    // 8 KB: cross-rowgroup reduce
    const int b = blockIdx.x, lc = blockIdx.y;
    const int tid = threadIdx.x;
    const int cg = tid & 63;          // col group: cols cg*8..+7 (512 cols)
    const int lg = tid >> 6;          // row group: 32 rows each

    *(float4*)&AsL[tid * 4] = *(const float4*)&Asg[(size_t)b * 8192 + lc * 1024 + tid * 4];
    __syncthreads();

    float acc[8][8] = {};
    const bf16* hb = h + ((size_t)b * 1024 + lc * 128 + lg * 32) * 512 + cg * 8;
    #pragma unroll 2
    for (int l = 0; l < 32; l++) {
        bf16x8 hv = *(const bf16x8*)&hb[(size_t)l * 512];
        float hf[8];
        #pragma unroll
        for (int k = 0; k < 8; k++) hf[k] = (float)hv[k];
        const float* ar = &AsL[(lg * 32 + l) * 8];
        #pragma unroll
        for (int r = 0; r < 8; r++)
            #pragma unroll
            for (int k = 0; k < 8; k++)
                acc[r][k] += ar[r] * hf[k];
    }

    float* pb = pp + ((size_t)lc * 64 + b) * 4096;
    #pragma unroll
    for (int r = 0; r < 8; r++) {
        __syncthreads();
        *(float4*)&red[tid * 8]     = *(float4*)&acc[r][0];
        *(float4*)&red[tid * 8 + 4] = *(float4*)&acc[r][4];
        __syncthreads();
        if (tid < 64) {
            #pragma unroll
            for (int k = 0; k < 8; k++) {
                float v = red[tid * 8 + k] + red[(tid + 64) * 8 + k]
                        + red[(tid + 128) * 8 + k] + red[(tid + 192) * 8 + k];
                pb[r * 512 + tid * 8 + k] = v;
            }
        }
    }
}

// ---------------------------------------------------------------------------
// head pass 1: zpart[kc][b][c] = feat-chunk @ Wo1-slice. grid (64, 9),
// 128 thr — the high-TLP shape (576 blocks). Plain stores (no atomic,
// no memset; round-7 fusion regressed to 80us at 64 blocks from latency).
// ---------------------------------------------------------------------------
__global__ __launch_bounds__(128)
void head1(const float* __restrict__ pp, const float* __restrict__ p1,
           const float* __restrict__ p2, const float* __restrict__ Wo1,
           float* __restrict__ zpart)
{
    __shared__ float f[512];
    const int b = blockIdx.x, kc = blockIdx.y, tid = threadIdx.x;
    if (kc < 8) {
        for (int j = tid; j < 512; j += 128) {
            const size_t i = (size_t)kc * 512 + j;
            float s = 0.f;
            #pragma unroll
            for (int lc = 0; lc < 8; lc++)
                s += pp[((size_t)lc * 64 + b) * 4096 + i];
            f[j] = s;
        }
    } else {
        for (int j = tid; j < 256; j += 128) {
            float s = 0.f, s2 = 0.f;
            #pragma unroll
            for (int lc = 0; lc < 16; lc++) {
                s  += p1[((size_t)lc * 64 + b) * 256 + j];
                s2 += p2[((size_t)lc * 64 + b) * 256 + j];
            }
            float m = s * (1.f / 1024.f);
            float var = (s2 - s * m) * (1.f / 1023.f);
            f[j]       = m;
            f[256 + j] = sqrtf(fmaxf(var, 0.f));
        }
    }
    __syncthreads();
    const float* Wp = Wo1 + (size_t)kc * 512 * 128 + tid;
    float z = 0.f;
    #pragma unroll 8
    for (int j = 0; j < 512; j++) z += f[j] * Wp[(size_t)j * 128];
    zpart[((size_t)kc * 64 + b) * 128 + tid] = z;
}

// ---------------------------------------------------------------------------
// head pass 2: sum 9 zparts -> BN+relu -> @ Wo2 -> log_softmax; penalty
// from penb (deterministic, no atomics anywhere).
// ---------------------------------------------------------------------------
__global__ __launch_bounds__(128)
void head2(const float* __restrict__ zpart, const float* __restrict__ bo1,
           const float* __restrict__ go, const float* __restrict__ beo,
           const float* __restrict__ mo, const float* __restrict__ vo,
           const float* __restrict__ Wo2, const float* __restrict__ bo2,
           const float* __restrict__ penb, float* __restrict__ out)
{
    __shared__ float o[128];
    __shared__ float lg[4];
    const int b = blockIdx.x, tid = threadIdx.x;
    float z = 0.f;
    #pragma unroll
    for (int kc = 0; kc < 9; kc++)
        z += zpart[((size_t)kc * 64 + b) * 128 + tid];
    float s = go[tid] * rsqrtf(vo[tid] + EPS);
    float t = (bo1[tid] - mo[tid]) * s + beo[tid];
    float ov = z * s + t;
    o[tid] = ov > 0.f ? ov : 0.f;
    __syncthreads();
    if (tid < 4) {
        float acc = bo2[tid];
        for (int j = 0; j < 128; j++) acc += o[j] * Wo2[j * 4 + tid];
        lg[tid] = acc;
    }
    __syncthreads();
    if (tid == 0) {
        float m = fmaxf(fmaxf(lg[0], lg[1]), fmaxf(lg[2], lg[3]));
        float sum = 0.f;
        for (int k = 0; k < 4; k++) sum += expf(lg[k] - m);
        float lse = m + logf(sum);
        for (int k = 0; k < 4; k++) out[b * 4 + k] = lg[k] - lse;
        if (b == 0) {
            float psum = 0.f;
            for (int i = 0; i < 64; i++) psum += penb[i];
            out[256] = psum;
        }
    }
}

// ---------------------------------------------------------------------------
extern "C" void kernel_launch(void* const* d_in, const int* in_sizes, int n_in,
                              void* d_out, int out_size, void* d_ws, size_t ws_size,
                              hipStream_t stream)
{
    const float* x   = (const float*)d_in[0];
    const float* Wa  = (const float*)d_in[2];
    const float* Wo1 = (const float*)d_in[3];
    const float* bo1 = (const float*)d_in[4];
    const float* go  = (const float*)d_in[5];
    const float* beo = (const float*)d_in[6];
    const float* mo  = (const float*)d_in[7];
    const float* vo  = (const float*)d_in[8];
    const float* Wo2 = (const float*)d_in[9];
    const float* bo2 = (const float*)d_in[10];
    const float *W[4], *bb[4], *gg[4], *be[4], *mm[4], *vv[4];
    for (int l = 0; l < 4; l++) {
        W[l]  = (const float*)d_in[11 + 6 * l + 0];
        bb[l] = (const float*)d_in[11 + 6 * l + 1];
        gg[l] = (const float*)d_in[11 + 6 * l + 2];
        be[l] = (const float*)d_in[11 + 6 * l + 3];
        mm[l] = (const float*)d_in[11 + 6 * l + 4];
        vv[l] = (const float*)d_in[11 + 6 * l + 5];
    }

    char* w = (char*)d_ws;
    bf16* xb  = (bf16*)w;  w += (size_t)65536 * 256 * 2;   // 32 MB
    bf16* hA  = (bf16*)w;  w += (size_t)65536 * 512 * 2;   // 64 MB
    bf16* hB  = (bf16*)w;  w += (size_t)65536 * 512 * 2;   // 64 MB
    bf16* w1t = (bf16*)w;  w += (size_t)512 * 256 * 2;
    bf16* w2t = (bf16*)w;  w += (size_t)512 * 512 * 2;
    bf16* w3t = (bf16*)w;  w += (size_t)512 * 512 * 2;
    bf16* w4t = (bf16*)w;  w += (size_t)512 * 512 * 2;
    float* sb = (float*)w; w += (size_t)4 * 1024 * 4;      // [layer][s|t][512]
    float* Ab = (float*)w; w += (size_t)65536 * 8 * 4;
    float* As = (float*)w; w += (size_t)65536 * 8 * 4;
    float* pp = (float*)w; w += (size_t)8 * 64 * 4096 * 4; // pooled partials
    float* p1 = (float*)w; w += (size_t)16 * 64 * 256 * 4;
    float* p2 = (float*)w; w += (size_t)16 * 64 * 256 * 4;
    float* zpart = (float*)w; w += (size_t)9 * 64 * 128 * 4;
    float* penb = (float*)w; w += (size_t)64 * 4;

    prep_fused<<<4616, 256, 0, stream>>>(
        x, xb, p1, p2,
        W[0], W[1], W[2], W[3], w1t, w2t, w3t, w4t,
        bb[0], gg[0], be[0], mm[0], vv[0],
        bb[1], gg[1], be[1], mm[1], vv[1],
        bb[2], gg[2], be[2], mm[2], vv[2],
        bb[3], gg[3], be[3], mm[3], vv[3], sb);

    gemm_bt<256><<<512, 512, 0, stream>>>(xb, w1t, sb + 0,    sb + 512,  hA);
    gemm_bt<512><<<512, 512, 0, stream>>>(hA, w2t, sb + 1024, sb + 1536, hB);
    gemm_bt<512><<<512, 512, 0, stream>>>(hB, w3t, sb + 2048, sb + 2560, hA);
    gemm_bt<512><<<512, 512, 0, stream>>>(hA, w4t, sb + 3072, sb + 3584, hB);

    compute_A<<<2048, 256, 0, stream>>>(hB, Wa, Ab);
    seg_softmax<<<64, 1024, 0, stream>>>(Ab, As, penb);
    pooled_k<<<dim3(64, 8), 256, 0, stream>>>(As, hB, pp);
    head1<<<dim3(64, 9), 128, 0, stream>>>(pp, p1, p2, Wo1, zpart);
    head2<<<64, 128, 0, stream>>>(zpart, bo1, go, beo, mo, vo, Wo2, bo2,
                                  penb, (float*)d_out);
}